// Round 6
// baseline (103.172 us; speedup 1.0000x reference)
//
#include <hip/hip_runtime.h>

#define HW_  4096
#define DV   1048576    // 256*4096 per batch

using bf16x8 = __attribute__((ext_vector_type(8))) __bf16;
using f32x4  = __attribute__((ext_vector_type(4))) float;

static __device__ __forceinline__ unsigned short f2bf(float f) {
    union { float f; unsigned u; } v; v.f = f;
    unsigned r = v.u + 0x7FFFu + ((v.u >> 16) & 1u);
    return (unsigned short)(r >> 16);
}
static __device__ __forceinline__ float bf2f(unsigned short h) {
    union { unsigned u; float f; } v; v.u = ((unsigned)h) << 16;
    return v.f;
}

// ---------------- pack weights into MFMA A-fragment layout:
// addr(m,c) = (m>>4)*4096 + (c>>3)*128 + (m&15)*8 + (c&7)
// WhF/WlF = hi/lo split of [wq;wk] (64x256); WvF = bf16 wv (256x256).
__global__ __launch_bounds__(256) void k_pack(const float* wq, const float* wk, const float* wv,
                                              unsigned short* WhF, unsigned short* WlF, unsigned short* WvF) {
    int idx = blockIdx.x * 256 + threadIdx.x;   // 81920 total
    if (idx < 16384) {
        int i = idx;
        int mt = i >> 12, cg = (i >> 7) & 31, ml = (i >> 3) & 15, cl = i & 7;
        int m = mt * 16 + ml, c = cg * 8 + cl;
        float f = (m < 32) ? wq[m * 256 + c] : wk[(m - 32) * 256 + c];
        unsigned short hi = f2bf(f);
        WhF[i] = hi;
        WlF[i] = f2bf(f - bf2f(hi));
    } else {
        int i = idx - 16384;
        int mt = i >> 12, kt = (i >> 7) & 31, lr = (i >> 3) & 15, j = i & 7;
        int m = mt * 16 + lr, c = kt * 8 + j;
        WvF[i] = f2bf(wv[m * 256 + c]);
    }
}

// ---------------- fused qk-GEMM + scores. Block: n-slice of 16, ALL 16 batches.
// Wave w = batch w. Split-bf16 q,k in acc; then acc -> LDS frag layout; wave 0 does the
// 16x16 Gram via 48 MFMA; writes 128 partial scores Sp[blk][p].
__global__ __launch_bounds__(1024, 4) void k_qks(const unsigned short* __restrict__ WhF,
                                                 const unsigned short* __restrict__ WlF,
                                                 const float* __restrict__ x,
                                                 const float* __restrict__ bq, const float* __restrict__ bk,
                                                 float* __restrict__ Sp) {
    __shared__ __align__(16) __bf16 SB[2][16][2][1024];   // 128 KB: [buf][b][hi/lo][frag elems of 64k x 16n]
    int n0 = blockIdx.x * 16;
    int t = threadIdx.x;
    int lane = t & 63, wid = t >> 6;      // wid = batch
    int lr = lane & 15, kg = lane >> 4;
    int sn = t & 15, sk = t >> 4;         // staging site: k 0..63, n 0..15
    int saddr = ((sk >> 3) * 16 + sn) * 8 + (sk & 7);

    f32x4 acc[4];
    #pragma unroll
    for (int mf = 0; mf < 4; mf++) acc[mf] = (f32x4){0.f, 0.f, 0.f, 0.f};

    float xv[16];
    const float* xs0 = x + (size_t)sk * HW_ + n0 + sn;
    #pragma unroll
    for (int bp = 0; bp < 16; bp++) xv[bp] = xs0[(size_t)bp * DV];
    #pragma unroll
    for (int bp = 0; bp < 16; bp++) {
        float v = xv[bp]; __bf16 h = (__bf16)v;
        SB[0][bp][0][saddr] = h;
        SB[0][bp][1][saddr] = (__bf16)(v - (float)h);
    }
    __syncthreads();

    const unsigned short* Abh = WhF + lane * 8;
    const unsigned short* Abl = WlF + lane * 8;

    for (int c = 0; c < 4; c++) {
        int cur = c & 1;
        if (c < 3) {
            const float* xp = x + (size_t)((c + 1) * 64 + sk) * HW_ + n0 + sn;
            #pragma unroll
            for (int bp = 0; bp < 16; bp++) xv[bp] = xp[(size_t)bp * DV];
        }
        #pragma unroll
        for (int sub = 0; sub < 2; sub++) {
            int kcg = c * 2 + sub;
            bf16x8 bh = *(const bf16x8*)&SB[cur][wid][0][sub * 512 + lane * 8];
            bf16x8 bl = *(const bf16x8*)&SB[cur][wid][1][sub * 512 + lane * 8];
            #pragma unroll
            for (int mf = 0; mf < 4; mf++) {
                bf16x8 ah = *(const bf16x8*)(Abh + mf * 4096 + kcg * 512);
                bf16x8 al = *(const bf16x8*)(Abl + mf * 4096 + kcg * 512);
                acc[mf] = __builtin_amdgcn_mfma_f32_16x16x32_bf16(ah, bh, acc[mf], 0, 0, 0);
                acc[mf] = __builtin_amdgcn_mfma_f32_16x16x32_bf16(ah, bl, acc[mf], 0, 0, 0);
                acc[mf] = __builtin_amdgcn_mfma_f32_16x16x32_bf16(al, bh, acc[mf], 0, 0, 0);
            }
        }
        if (c < 3) {
            int nb = cur ^ 1;
            #pragma unroll
            for (int bp = 0; bp < 16; bp++) {
                float v = xv[bp]; __bf16 h = (__bf16)v;
                SB[nb][bp][0][saddr] = h;
                SB[nb][bp][1][saddr] = (__bf16)(v - (float)h);
            }
        }
        __syncthreads();
    }

    // q/k (bias added, hi/lo split) -> LDS in frag layout [qk][part][8192]
    __bf16* F = &SB[0][0][0][0];
    int b = wid;
    #pragma unroll
    for (int mf = 0; mf < 4; mf++) {
        #pragma unroll
        for (int i = 0; i < 4; i++) {
            int row64 = mf * 16 + kg * 4 + i;
            float val = acc[mf][i] + ((row64 < 32) ? bq[row64] : bk[row64 - 32]);
            int qk = row64 >> 5;
            int r  = row64 & 31;
            int col = r * 16 + lr;                 // contraction index (r,n) flattened, 0..511
            __bf16 h = (__bf16)val;
            __bf16 l = (__bf16)(val - (float)h);
            int base = qk * 16384 + ((col >> 3) * 16 + b) * 8 + (col & 7);
            F[base] = h;
            F[base + 8192] = l;
        }
    }
    __syncthreads();

    if (wid == 0) {
        f32x4 S = (f32x4){0.f, 0.f, 0.f, 0.f};
        #pragma unroll
        for (int s = 0; s < 16; s++) {
            bf16x8 qh = *(const bf16x8*)&F[s * 512 + lane * 8];
            bf16x8 ql = *(const bf16x8*)&F[8192 + s * 512 + lane * 8];
            bf16x8 kh = *(const bf16x8*)&F[16384 + s * 512 + lane * 8];
            bf16x8 kl = *(const bf16x8*)&F[24576 + s * 512 + lane * 8];
            S = __builtin_amdgcn_mfma_f32_16x16x32_bf16(qh, kh, S, 0, 0, 0);
            S = __builtin_amdgcn_mfma_f32_16x16x32_bf16(qh, kl, S, 0, 0, 0);
            S = __builtin_amdgcn_mfma_f32_16x16x32_bf16(ql, kh, S, 0, 0, 0);
        }
        #pragma unroll
        for (int i = 0; i < 4; i++) {
            int bb = kg * 4 + i;                   // D row = q batch
            int bp = lr;                           // D col = k batch
            int h = bb >> 2, w = bb & 3;
            float val = S[i];
            if ((bp & 3) == w) Sp[(size_t)blockIdx.x * 128 + bb * 8 + (bp >> 2)] = val;
            if ((bp >> 2) == h) Sp[(size_t)blockIdx.x * 128 + bb * 8 + 4 + (bp & 3)] = val;
        }
    }
}

// ---------------- reduce partial scores + softmax + fold gamma -> M [0..255] + rowsum [256..271]
__global__ void k_softmax3(const float* __restrict__ Sp, const float* __restrict__ gamma,
                           float* __restrict__ Mm) {
    __shared__ float SS[128];
    int t = threadIdx.x;                           // 128 threads
    float s = 0.f;
    #pragma unroll 8
    for (int blk = 0; blk < 256; blk++) s += Sp[(size_t)blk * 128 + t];
    SS[t] = s;
    __syncthreads();
    if (t < 16) {
        int b = t, h = b >> 2, w = b & 3;
        float e[8];
        for (int j = 0; j < 8; j++) e[j] = SS[b * 8 + j];
        e[h] = -INFINITY;                          // masked diagonal of eH
        float mx = e[0];
        for (int j = 1; j < 8; j++) mx = fmaxf(mx, e[j]);
        float aa[8], sum = 0.f;
        for (int j = 0; j < 8; j++) { aa[j] = expf(e[j] - mx); sum += aa[j]; }
        float inv = 1.0f / sum;
        float g = gamma[0];
        float row[16];
        for (int c = 0; c < 16; c++) row[c] = 0.f;
        for (int gg = 0; gg < 4; gg++) if (gg != h) row[gg * 4 + w] += aa[gg] * inv;     // eH partners
        for (int gg = 0; gg < 4; gg++) row[h * 4 + gg] += aa[4 + gg] * inv;              // eW partners
        for (int c = 0; c < 16; c++) Mm[b * 16 + c] = row[c] * g;
        Mm[256 + b] = g;                           // rowsum of M
    }
}

// ---------------- fused v-GEMM + batch-mix + bias + residual -> out.
// Block: n-slice of 16, ALL batches, ALL 256 m. Wave w = m-frag w. u[bp] = Wv·x[bp] in acc;
// epilogue mixes accs (7-sparse M), adds rs*bv + fp32 residual, writes d_out.
__global__ __launch_bounds__(1024, 4) void k_fused(const unsigned short* __restrict__ WvF,
                                                   const float* __restrict__ x,
                                                   const float* __restrict__ bv,
                                                   const float* __restrict__ Mm,
                                                   float* __restrict__ out) {
    __shared__ __align__(16) __bf16 XB[2][16][1024];      // 64 KB: [buf][b][frag elems of 64k x 16n]
    int n0 = blockIdx.x * 16;
    int t = threadIdx.x;
    int lane = t & 63, wid = t >> 6;      // wid = m-frag (m rows wid*16..wid*16+15)
    int lr = lane & 15, kg = lane >> 4;
    int sn = t & 15, sk = t >> 4;
    int saddr = ((sk >> 3) * 16 + sn) * 8 + (sk & 7);

    f32x4 u[16];
    #pragma unroll
    for (int b = 0; b < 16; b++) u[b] = (f32x4){0.f, 0.f, 0.f, 0.f};

    float xv[16];
    const float* xs0 = x + (size_t)sk * HW_ + n0 + sn;
    #pragma unroll
    for (int bp = 0; bp < 16; bp++) xv[bp] = xs0[(size_t)bp * DV];
    #pragma unroll
    for (int bp = 0; bp < 16; bp++) XB[0][bp][saddr] = (__bf16)xv[bp];
    __syncthreads();

    const unsigned short* Ab = WvF + (size_t)wid * 4096 + lane * 8;

    for (int c = 0; c < 4; c++) {
        int cur = c & 1;
        if (c < 3) {
            const float* xp = x + (size_t)((c + 1) * 64 + sk) * HW_ + n0 + sn;
            #pragma unroll
            for (int bp = 0; bp < 16; bp++) xv[bp] = xp[(size_t)bp * DV];
        }
        #pragma unroll
        for (int sub = 0; sub < 2; sub++) {
            bf16x8 a = *(const bf16x8*)(Ab + (c * 2 + sub) * 512);
            #pragma unroll
            for (int b = 0; b < 16; b++) {
                bf16x8 bb = *(const bf16x8*)&XB[cur][b][sub * 512 + lane * 8];
                u[b] = __builtin_amdgcn_mfma_f32_16x16x32_bf16(a, bb, u[b], 0, 0, 0);
            }
        }
        if (c < 3) {
            int nb = cur ^ 1;
            #pragma unroll
            for (int bp = 0; bp < 16; bp++) XB[nb][bp][saddr] = (__bf16)xv[bp];
        }
        __syncthreads();
    }

    // epilogue: mix u across batches (7-sparse), + rs*bv + residual, write
    #pragma unroll
    for (int b = 0; b < 16; b++) {
        int h = b >> 2, w = b & 3;
        f32x4 m = (f32x4){0.f, 0.f, 0.f, 0.f};
        #pragma unroll
        for (int g = 0; g < 4; g++) {
            if (g != h) m += Mm[b * 16 + g * 4 + w] * u[g * 4 + w];
            m += Mm[b * 16 + h * 4 + g] * u[h * 4 + g];
        }
        float rs = Mm[256 + b];
        #pragma unroll
        for (int i = 0; i < 4; i++) {
            int mrow = wid * 16 + kg * 4 + i;
            size_t idx = (size_t)b * DV + (size_t)mrow * HW_ + n0 + lr;
            out[idx] = m[i] + rs * bv[mrow] + x[idx];
        }
    }
}

extern "C" void kernel_launch(void* const* d_in, const int* in_sizes, int n_in,
                              void* d_out, int out_size, void* d_ws, size_t ws_size,
                              hipStream_t stream) {
    (void)in_sizes; (void)n_in; (void)out_size; (void)ws_size;
    const float* x     = (const float*)d_in[0];
    const float* wq    = (const float*)d_in[1];
    const float* bq    = (const float*)d_in[2];
    const float* wk    = (const float*)d_in[3];
    const float* bk    = (const float*)d_in[4];
    const float* wv    = (const float*)d_in[5];
    const float* bv    = (const float*)d_in[6];
    const float* gamma = (const float*)d_in[7];

    char* ws = (char*)d_ws;
    // ws layout: WhF 32768 | WlF 32768 | WvF 131072 | Sp 131072 | Mm 1088  (~329 KB)
    unsigned short* WhF = (unsigned short*)(ws + 0);
    unsigned short* WlF = (unsigned short*)(ws + 32768);
    unsigned short* WvF = (unsigned short*)(ws + 65536);
    float*          Sp  = (float*)(ws + 196608);
    float*          Mm  = (float*)(ws + 327680);
    float*          vo  = (float*)d_out;

    k_pack     <<<320, 256, 0, stream>>>(wq, wk, wv, WhF, WlF, WvF);
    k_qks      <<<256, 1024, 0, stream>>>(WhF, WlF, x, bq, bk, Sp);
    k_softmax3 <<<1, 128, 0, stream>>>(Sp, gamma, Mm);
    k_fused    <<<256, 1024, 0, stream>>>(WvF, x, bv, Mm, vo);
}

// Round 7
// 98.442 us; speedup vs baseline: 1.0480x; 1.0480x over previous
//
#include <hip/hip_runtime.h>

#define HW_  4096
#define DV   1048576    // 256*4096 per batch

using bf16x8 = __attribute__((ext_vector_type(8))) __bf16;
using f32x4  = __attribute__((ext_vector_type(4))) float;

static __device__ __forceinline__ unsigned short f2bf(float f) {
    union { float f; unsigned u; } v; v.f = f;
    unsigned r = v.u + 0x7FFFu + ((v.u >> 16) & 1u);
    return (unsigned short)(r >> 16);
}
static __device__ __forceinline__ float bf2f(unsigned short h) {
    union { unsigned u; float f; } v; v.u = ((unsigned)h) << 16;
    return v.f;
}

// ---------------- pack weights into MFMA A-fragment layout:
// addr(m,c) = (m>>4)*4096 + (c>>3)*128 + (m&15)*8 + (c&7)
__global__ __launch_bounds__(256) void k_pack(const float* wq, const float* wk, const float* wv,
                                              unsigned short* WhF, unsigned short* WlF, unsigned short* WvF) {
    int idx = blockIdx.x * 256 + threadIdx.x;   // 81920 total
    if (idx < 16384) {
        int i = idx;
        int mt = i >> 12, cg = (i >> 7) & 31, ml = (i >> 3) & 15, cl = i & 7;
        int m = mt * 16 + ml, c = cg * 8 + cl;
        float f = (m < 32) ? wq[m * 256 + c] : wk[(m - 32) * 256 + c];
        unsigned short hi = f2bf(f);
        WhF[i] = hi;
        WlF[i] = f2bf(f - bf2f(hi));
    } else {
        int i = idx - 16384;
        int mt = i >> 12, kt = (i >> 7) & 31, lr = (i >> 3) & 15, j = i & 7;
        int m = mt * 16 + lr, c = kt * 8 + j;
        WvF[i] = f2bf(wv[m * 256 + c]);
    }
}

// ---------------- fused qk-GEMM + scores (16-n blocks). Staging vectorized f32x4 x 4bp,
// sigma-swizzled LDS frag layout. Wave w = batch w; wave 0 does the Gram; Sp transposed [pair][blk].
__global__ __launch_bounds__(1024, 4) void k_qks(const unsigned short* __restrict__ WhF,
                                                 const unsigned short* __restrict__ WlF,
                                                 const float* __restrict__ x,
                                                 const float* __restrict__ bq, const float* __restrict__ bk,
                                                 float* __restrict__ Sp) {
    __shared__ __align__(16) __bf16 SBf[2 * 16 * 2 * 1024];   // [buf][bp][hl][1024] = 128 KB
    int n0 = blockIdx.x * 16;
    int t = threadIdx.x;
    int lane = t & 63, wid = t >> 6;
    int lr = lane & 15, kg = lane >> 4;
    int n4 = t & 3, sk = (t >> 2) & 63, bpg = t >> 8;
    int siglr = ((lr & 3) << 2) | (lr >> 2);

    f32x4 acc[4];
    #pragma unroll
    for (int mf = 0; mf < 4; mf++) acc[mf] = (f32x4){0.f, 0.f, 0.f, 0.f};

    f32x4 xv[4];
    #pragma unroll
    for (int bpi = 0; bpi < 4; bpi++)
        xv[bpi] = *(const f32x4*)(x + (size_t)(bpg * 4 + bpi) * DV + (size_t)sk * HW_ + n0 + n4 * 4);
    #pragma unroll
    for (int bpi = 0; bpi < 4; bpi++) {
        int bp = bpg * 4 + bpi;
        __bf16* basep = SBf + ((0 * 16 + bp) * 2) * 1024 + (sk >> 5) * 512 + (((sk & 31) >> 3) * 16) * 8 + (sk & 7);
        #pragma unroll
        for (int e = 0; e < 4; e++) {
            float v = xv[bpi][e];
            __bf16 h = (__bf16)v;
            int off = ((e << 2) | n4) * 8;
            basep[off] = h;
            basep[off + 1024] = (__bf16)(v - (float)h);
        }
    }
    __syncthreads();

    const unsigned short* Abh = WhF + lane * 8;
    const unsigned short* Abl = WlF + lane * 8;

    for (int c = 0; c < 4; c++) {
        int cur = c & 1;
        if (c < 3) {
            #pragma unroll
            for (int bpi = 0; bpi < 4; bpi++)
                xv[bpi] = *(const f32x4*)(x + (size_t)(bpg * 4 + bpi) * DV + (size_t)((c + 1) * 64 + sk) * HW_ + n0 + n4 * 4);
        }
        #pragma unroll
        for (int sub = 0; sub < 2; sub++) {
            int kcg = c * 2 + sub;
            const __bf16* bptr = SBf + ((cur * 16 + wid) * 2) * 1024 + sub * 512 + (kg * 16 + siglr) * 8;
            bf16x8 bh = *(const bf16x8*)bptr;
            bf16x8 bl = *(const bf16x8*)(bptr + 1024);
            #pragma unroll
            for (int mf = 0; mf < 4; mf++) {
                bf16x8 ah = *(const bf16x8*)(Abh + mf * 4096 + kcg * 512);
                bf16x8 al = *(const bf16x8*)(Abl + mf * 4096 + kcg * 512);
                acc[mf] = __builtin_amdgcn_mfma_f32_16x16x32_bf16(ah, bh, acc[mf], 0, 0, 0);
                acc[mf] = __builtin_amdgcn_mfma_f32_16x16x32_bf16(ah, bl, acc[mf], 0, 0, 0);
                acc[mf] = __builtin_amdgcn_mfma_f32_16x16x32_bf16(al, bh, acc[mf], 0, 0, 0);
            }
        }
        if (c < 3) {
            int nb = cur ^ 1;
            #pragma unroll
            for (int bpi = 0; bpi < 4; bpi++) {
                int bp = bpg * 4 + bpi;
                __bf16* basep = SBf + ((nb * 16 + bp) * 2) * 1024 + (sk >> 5) * 512 + (((sk & 31) >> 3) * 16) * 8 + (sk & 7);
                #pragma unroll
                for (int e = 0; e < 4; e++) {
                    float v = xv[bpi][e];
                    __bf16 h = (__bf16)v;
                    int off = ((e << 2) | n4) * 8;
                    basep[off] = h;
                    basep[off + 1024] = (__bf16)(v - (float)h);
                }
            }
        }
        __syncthreads();
    }

    // q/k (bias added, hi/lo split) -> LDS frag layout [qk][part][8192]
    __bf16* F = SBf;
    int b = wid;
    #pragma unroll
    for (int mf = 0; mf < 4; mf++) {
        #pragma unroll
        for (int i = 0; i < 4; i++) {
            int row64 = mf * 16 + kg * 4 + i;
            float val = acc[mf][i] + ((row64 < 32) ? bq[row64] : bk[row64 - 32]);
            int qk = row64 >> 5;
            int r  = row64 & 31;
            int col = r * 16 + lr;                 // contraction index, 0..511
            __bf16 h = (__bf16)val;
            __bf16 l = (__bf16)(val - (float)h);
            int base = qk * 16384 + ((col >> 3) * 16 + b) * 8 + (col & 7);
            F[base] = h;
            F[base + 8192] = l;
        }
    }
    __syncthreads();

    if (wid == 0) {
        f32x4 S = (f32x4){0.f, 0.f, 0.f, 0.f};
        #pragma unroll
        for (int s = 0; s < 16; s++) {
            bf16x8 qh = *(const bf16x8*)&F[s * 512 + lane * 8];
            bf16x8 ql = *(const bf16x8*)&F[8192 + s * 512 + lane * 8];
            bf16x8 kh = *(const bf16x8*)&F[16384 + s * 512 + lane * 8];
            bf16x8 kl = *(const bf16x8*)&F[24576 + s * 512 + lane * 8];
            S = __builtin_amdgcn_mfma_f32_16x16x32_bf16(qh, kh, S, 0, 0, 0);
            S = __builtin_amdgcn_mfma_f32_16x16x32_bf16(qh, kl, S, 0, 0, 0);
            S = __builtin_amdgcn_mfma_f32_16x16x32_bf16(ql, kh, S, 0, 0, 0);
        }
        #pragma unroll
        for (int i = 0; i < 4; i++) {
            int bb = kg * 4 + i;                   // D row = q batch
            int bp = lr;                           // D col = k batch
            int h = bb >> 2, w = bb & 3;
            float val = S[i];
            if ((bp & 3) == w)  Sp[(size_t)(bb * 8 + (bp >> 2)) * 256 + blockIdx.x] = val;
            if ((bp >> 2) == h) Sp[(size_t)(bb * 8 + 4 + (bp & 3)) * 256 + blockIdx.x] = val;
        }
    }
}

// ---------------- reduce partials (contiguous per pair) + softmax + gamma -> M + rowsum
__global__ void k_softmax3(const float* __restrict__ Sp, const float* __restrict__ gamma,
                           float* __restrict__ Mm) {
    __shared__ float SS[128];
    int t = threadIdx.x;                           // 128 threads = pairs
    const f32x4* s4 = (const f32x4*)(Sp + (size_t)t * 256);
    f32x4 a = (f32x4){0.f, 0.f, 0.f, 0.f};
    #pragma unroll 8
    for (int i = 0; i < 64; i++) a += s4[i];
    SS[t] = a[0] + a[1] + a[2] + a[3];
    __syncthreads();
    if (t < 16) {
        int b = t, h = b >> 2, w = b & 3;
        float e[8];
        for (int j = 0; j < 8; j++) e[j] = SS[b * 8 + j];
        e[h] = -INFINITY;
        float mx = e[0];
        for (int j = 1; j < 8; j++) mx = fmaxf(mx, e[j]);
        float aa[8], sum = 0.f;
        for (int j = 0; j < 8; j++) { aa[j] = expf(e[j] - mx); sum += aa[j]; }
        float inv = 1.0f / sum;
        float g = gamma[0];
        float row[16];
        for (int c = 0; c < 16; c++) row[c] = 0.f;
        for (int gg = 0; gg < 4; gg++) if (gg != h) row[gg * 4 + w] += aa[gg] * inv;
        for (int gg = 0; gg < 4; gg++) row[h * 4 + gg] += aa[4 + gg] * inv;
        for (int c = 0; c < 16; c++) Mm[b * 16 + c] = row[c] * g;
        Mm[256 + b] = g;
    }
}

// ---------------- fused v-GEMM + mix + bias + residual. Block: 64 m x 64 n x 16 b.
// XCD-grouped m-split (4 m-blocks of an n-slice share x reads in one L2).
// Epilogue via LDS transpose: residual reads + out writes are coalesced f32x4.
__global__ __launch_bounds__(1024, 4) void k_fused(const unsigned short* __restrict__ WvF,
                                                   const float* __restrict__ x,
                                                   const float* __restrict__ bv,
                                                   const float* __restrict__ Mm,
                                                   float* __restrict__ out) {
    __shared__ __align__(16) char RAW[131072];
    __bf16* XBf = (__bf16*)RAW;                   // [2][16 bp][4 ng][512]
    int bid = blockIdx.x;
    int xg = bid & 7, r = bid >> 3;
    int nblk = xg * 8 + (r >> 2), mblk = r & 3;   // 4 m-blocks of an n-slice -> same XCD
    int n0 = nblk * 64, m0 = mblk * 64;
    int t = threadIdx.x;
    int lane = t & 63, wid = t >> 6;
    int wm = wid & 3, wn = wid >> 2;              // wave tile: 16m x 16n x 16b
    int lr = lane & 15, kg = lane >> 4;
    int n4 = t & 15, sk = (t >> 4) & 31, bpg = t >> 9;
    int sigr = (((lr & 3) << 2) | (lr >> 2)) ^ (wn << 1);  // read-side swizzled slot

    f32x4 u[16];
    #pragma unroll
    for (int b = 0; b < 16; b++) u[b] = (f32x4){0.f, 0.f, 0.f, 0.f};

    f32x4 xv[8];
    #pragma unroll
    for (int bpi = 0; bpi < 8; bpi++)
        xv[bpi] = *(const f32x4*)(x + (size_t)(bpg * 8 + bpi) * DV + (size_t)sk * HW_ + n0 + n4 * 4);
    #pragma unroll
    for (int bpi = 0; bpi < 8; bpi++) {
        int bp = bpg * 8 + bpi;
        __bf16* basep = XBf + ((0 * 16 + bp) * 4 + (n4 >> 2)) * 512 + ((sk >> 3) * 16) * 8 + (sk & 7);
        #pragma unroll
        for (int e = 0; e < 4; e++) {
            int s = ((e << 2) | (n4 & 3)) ^ ((n4 >> 2) << 1);
            basep[s * 8] = (__bf16)xv[bpi][e];
        }
    }
    __syncthreads();

    for (int c = 0; c < 8; c++) {
        int cur = c & 1;
        if (c < 7) {
            #pragma unroll
            for (int bpi = 0; bpi < 8; bpi++)
                xv[bpi] = *(const f32x4*)(x + (size_t)(bpg * 8 + bpi) * DV + (size_t)((c + 1) * 32 + sk) * HW_ + n0 + n4 * 4);
        }
        bf16x8 a = *(const bf16x8*)(WvF + (size_t)(mblk * 4 + wm) * 4096 + c * 512 + lane * 8);
        const __bf16* bbase = XBf + ((cur * 16) * 4 + wn) * 512 + (kg * 16 + sigr) * 8;
        #pragma unroll
        for (int bp = 0; bp < 16; bp++) {
            bf16x8 bb = *(const bf16x8*)(bbase + bp * 2048);
            u[bp] = __builtin_amdgcn_mfma_f32_16x16x32_bf16(a, bb, u[bp], 0, 0, 0);
        }
        if (c < 7) {
            int nb = cur ^ 1;
            #pragma unroll
            for (int bpi = 0; bpi < 8; bpi++) {
                int bp = bpg * 8 + bpi;
                __bf16* basep = XBf + ((nb * 16 + bp) * 4 + (n4 >> 2)) * 512 + ((sk >> 3) * 16) * 8 + (sk & 7);
                #pragma unroll
                for (int e = 0; e < 4; e++) {
                    int s = ((e << 2) | (n4 & 3)) ^ ((n4 >> 2) << 1);
                    basep[s * 8] = (__bf16)xv[bpi][e];
                }
            }
        }
        __syncthreads();
    }

    // epilogue: mix in-reg, stage through LDS [4][64][68] fp32, coalesced residual+store
    int mrow0 = m0 + wm * 16 + kg * 4;
    f32x4 bv4 = (f32x4){bv[mrow0], bv[mrow0 + 1], bv[mrow0 + 2], bv[mrow0 + 3]};
    float* LD = (float*)RAW;                       // [4][64][68] = 69632 B
    int b2 = t >> 8, mr = (t >> 2) & 63, nq = t & 3;
    for (int bg = 0; bg < 4; bg++) {
        #pragma unroll
        for (int bi = 0; bi < 4; bi++) {
            int b = bg * 4 + bi, h = b >> 2, w = b & 3;
            f32x4 mo = (f32x4){0.f, 0.f, 0.f, 0.f};
            #pragma unroll
            for (int g = 0; g < 4; g++) {
                if (g != h) mo += Mm[b * 16 + g * 4 + w] * u[g * 4 + w];
                mo += Mm[b * 16 + h * 4 + g] * u[h * 4 + g];
            }
            mo += Mm[256 + b] * bv4;
            float* ld = LD + ((size_t)bi * 64 + wm * 16 + kg * 4) * 68 + wn * 16 + lr;
            #pragma unroll
            for (int i = 0; i < 4; i++) ld[i * 68] = mo[i];
        }
        __syncthreads();
        {
            int b = bg * 4 + b2;
            const float* lrow = LD + ((size_t)b2 * 64 + mr) * 68 + nq * 16;
            size_t gbase = (size_t)b * DV + (size_t)(m0 + mr) * HW_ + n0 + nq * 16;
            #pragma unroll
            for (int q = 0; q < 4; q++) {
                f32x4 o  = *(const f32x4*)(lrow + q * 4);
                f32x4 rr = *(const f32x4*)(x + gbase + q * 4);
                *(f32x4*)(out + gbase + q * 4) = o + rr;
            }
        }
        __syncthreads();
    }
}

extern "C" void kernel_launch(void* const* d_in, const int* in_sizes, int n_in,
                              void* d_out, int out_size, void* d_ws, size_t ws_size,
                              hipStream_t stream) {
    (void)in_sizes; (void)n_in; (void)out_size; (void)ws_size;
    const float* x     = (const float*)d_in[0];
    const float* wq    = (const float*)d_in[1];
    const float* bq    = (const float*)d_in[2];
    const float* wk    = (const float*)d_in[3];
    const float* bk    = (const float*)d_in[4];
    const float* wv    = (const float*)d_in[5];
    const float* bv    = (const float*)d_in[6];
    const float* gamma = (const float*)d_in[7];

    char* ws = (char*)d_ws;
    // ws layout: WhF 32768 | WlF 32768 | WvF 131072 | Sp 131072 | Mm 1088
    unsigned short* WhF = (unsigned short*)(ws + 0);
    unsigned short* WlF = (unsigned short*)(ws + 32768);
    unsigned short* WvF = (unsigned short*)(ws + 65536);
    float*          Sp  = (float*)(ws + 196608);
    float*          Mm  = (float*)(ws + 327680);
    float*          vo  = (float*)d_out;

    k_pack     <<<320, 256, 0, stream>>>(wq, wk, wv, WhF, WlF, WvF);
    k_qks      <<<256, 1024, 0, stream>>>(WhF, WlF, x, bq, bk, Sp);
    k_softmax3 <<<1, 128, 0, stream>>>(Sp, gamma, Mm);
    k_fused    <<<256, 1024, 0, stream>>>(WvF, x, bv, Mm, vo);
}

// Round 8
// 92.910 us; speedup vs baseline: 1.1105x; 1.0595x over previous
//
#include <hip/hip_runtime.h>

#define HW_  4096
#define DQK  131072     // 32*4096 per batch (q or k)
#define DV   1048576    // 256*4096 per batch

using bf16x8 = __attribute__((ext_vector_type(8))) __bf16;
using f32x4  = __attribute__((ext_vector_type(4))) float;

static __device__ __forceinline__ unsigned short f2bf(float f) {
    union { float f; unsigned u; } v; v.f = f;
    unsigned r = v.u + 0x7FFFu + ((v.u >> 16) & 1u);
    return (unsigned short)(r >> 16);
}
static __device__ __forceinline__ float bf2f(unsigned short h) {
    union { unsigned u; float f; } v; v.u = ((unsigned)h) << 16;
    return v.f;
}

// ---------------- pack weights into MFMA A-fragment layout:
// addr(m,c) = (m>>4)*4096 + (c>>3)*128 + (m&15)*8 + (c&7)
__global__ __launch_bounds__(256) void k_pack(const float* wq, const float* wk, const float* wv,
                                              unsigned short* WhF, unsigned short* WlF, unsigned short* WvF) {
    int idx = blockIdx.x * 256 + threadIdx.x;   // 81920 total
    if (idx < 16384) {
        int i = idx;
        int mt = i >> 12, cg = (i >> 7) & 31, ml = (i >> 3) & 15, cl = i & 7;
        int m = mt * 16 + ml, c = cg * 8 + cl;
        float f = (m < 32) ? wq[m * 256 + c] : wk[(m - 32) * 256 + c];
        unsigned short hi = f2bf(f);
        WhF[i] = hi;
        WlF[i] = f2bf(f - bf2f(hi));
    } else {
        int i = idx - 16384;
        int mt = i >> 12, kt = (i >> 7) & 31, lr = (i >> 3) & 15, j = i & 7;
        int m = mt * 16 + lr, c = kt * 8 + j;
        WvF[i] = f2bf(wv[m * 256 + c]);
    }
}

// ---------------- qk GEMM, split-bf16, NO LDS, no barriers (r5-validated).
// Wave tile 32m x 32n; wm: 0=q rows, 1=k rows. B-frags built in-register from direct x loads.
__global__ __launch_bounds__(256) void k_gemm_qk(const unsigned short* __restrict__ WhF,
                                                 const unsigned short* __restrict__ WlF,
                                                 const float* __restrict__ x,
                                                 const float* __restrict__ bq, const float* __restrict__ bk,
                                                 float* __restrict__ QF, float* __restrict__ KF) {
    int b  = blockIdx.y;
    int n0 = blockIdx.x * 64;
    int t = threadIdx.x;
    int lane = t & 63, wid = t >> 6;
    int wm = wid & 1, wn = wid >> 1;            // wm: q/k half; wn: n sub-tile
    int lr = lane & 15, kg = lane >> 4;

    const float* xb = x + (size_t)b * DV;
    const unsigned short* Ah0 = WhF + (size_t)(wm * 2) * 4096 + lane * 8;
    const unsigned short* Al0 = WlF + (size_t)(wm * 2) * 4096 + lane * 8;

    f32x4 acc[2][2];
    for (int mi = 0; mi < 2; mi++)
        for (int ni = 0; ni < 2; ni++) acc[mi][ni] = (f32x4){0.f, 0.f, 0.f, 0.f};

    for (int kk = 0; kk < 8; kk++) {
        bf16x8 ah[2], al[2];
        for (int mi = 0; mi < 2; mi++) {
            ah[mi] = *(const bf16x8*)(Ah0 + (size_t)mi * 4096 + kk * 512);
            al[mi] = *(const bf16x8*)(Al0 + (size_t)mi * 4096 + kk * 512);
        }
        bf16x8 bh[2], bl[2];
        int cbase = kk * 32 + kg * 8;
        for (int ni = 0; ni < 2; ni++) {
            const float* xp = xb + (size_t)cbase * HW_ + n0 + wn * 32 + ni * 16 + lr;
            #pragma unroll
            for (int j = 0; j < 8; j++) {
                float v = xp[(size_t)j * HW_];
                __bf16 h = (__bf16)v;
                bh[ni][j] = h;
                bl[ni][j] = (__bf16)(v - (float)h);
            }
        }
        for (int mi = 0; mi < 2; mi++)
            for (int ni = 0; ni < 2; ni++) {
                acc[mi][ni] = __builtin_amdgcn_mfma_f32_16x16x32_bf16(ah[mi], bh[ni], acc[mi][ni], 0, 0, 0);
                acc[mi][ni] = __builtin_amdgcn_mfma_f32_16x16x32_bf16(ah[mi], bl[ni], acc[mi][ni], 0, 0, 0);
                acc[mi][ni] = __builtin_amdgcn_mfma_f32_16x16x32_bf16(al[mi], bh[ni], acc[mi][ni], 0, 0, 0);
            }
    }

    float* dst = (wm == 0) ? QF : KF;
    const float* bias = (wm == 0) ? bq : bk;
    for (int mi = 0; mi < 2; mi++) {
        int mq0 = mi * 16 + kg * 4;
        for (int i = 0; i < 4; i++) {
            int mq = mq0 + i;
            float bs = bias[mq];
            for (int ni = 0; ni < 2; ni++) {
                int n = n0 + wn * 32 + ni * 16 + lr;
                dst[(size_t)b * DQK + (size_t)mq * HW_ + n] = acc[mi][ni][i] + bs;
            }
        }
    }
}

// ---------------- scores: 256 blocks, each owns a 512-elem d-slice for ALL 16 batches (r5-validated).
__global__ __launch_bounds__(256) void k_scores2(const float* __restrict__ QF, const float* __restrict__ KF,
                                                 float* __restrict__ Sp) {
    __shared__ float Ql[16][520], Kl[16][520];
    int s = blockIdx.x;                          // 0..255 : d-slice [s*512, s*512+512)
    int m = s >> 3, off = (s & 7) * 512;
    int t = threadIdx.x;
    for (int b = 0; b < 16; b++) {
        const float* qs = QF + (size_t)b * DQK + (size_t)m * HW_ + off;
        const float* ks = KF + (size_t)b * DQK + (size_t)m * HW_ + off;
        Ql[b][t]       = qs[t];
        Ql[b][t + 256] = qs[t + 256];
        Kl[b][t]       = ks[t];
        Kl[b][t + 256] = ks[t + 256];
    }
    __syncthreads();
    int p = t >> 1, h = t & 1;                   // 2 threads per pair
    int b = p >> 3, j = p & 7;
    int hb = b >> 2, wb = b & 3;
    int bp = (j < 4) ? (j * 4 + wb) : (hb * 4 + (j - 4));
    const f32x4* q4 = (const f32x4*)&Ql[b][h * 256];
    const f32x4* k4 = (const f32x4*)&Kl[bp][h * 256];
    f32x4 a4 = (f32x4){0.f, 0.f, 0.f, 0.f};
    for (int i = 0; i < 64; i++) a4 += q4[i] * k4[i];
    float sres = a4[0] + a4[1] + a4[2] + a4[3];
    sres += __shfl_xor(sres, 1);
    if (h == 0) Sp[(size_t)p * 256 + s] = sres;  // layout [pair][slice]
}

// ---------------- reduce slices + softmax + fold gamma -> M [0..255] + rowsum [256..271]
__global__ void k_softmax2(const float* __restrict__ Sp, const float* __restrict__ gamma,
                           float* __restrict__ Mm) {
    __shared__ float SS[128];
    int t = threadIdx.x;                         // 128 threads
    const f32x4* s4 = (const f32x4*)(Sp + (size_t)t * 256);
    f32x4 a = (f32x4){0.f, 0.f, 0.f, 0.f};
    for (int i = 0; i < 64; i++) a += s4[i];
    SS[t] = a[0] + a[1] + a[2] + a[3];
    __syncthreads();
    if (t < 16) {
        int b = t, h = b >> 2, w = b & 3;
        float e[8];
        for (int j = 0; j < 8; j++) e[j] = SS[b * 8 + j];
        e[h] = -INFINITY;
        float mx = e[0];
        for (int j = 1; j < 8; j++) mx = fmaxf(mx, e[j]);
        float aa[8], sum = 0.f;
        for (int j = 0; j < 8; j++) { aa[j] = expf(e[j] - mx); sum += aa[j]; }
        float inv = 1.0f / sum;
        float g = gamma[0];
        float row[16];
        for (int c = 0; c < 16; c++) row[c] = 0.f;
        for (int gg = 0; gg < 4; gg++) if (gg != h) row[gg * 4 + w] += aa[gg] * inv;
        for (int gg = 0; gg < 4; gg++) row[h * 4 + gg] += aa[4 + gg] * inv;
        for (int c = 0; c < 16; c++) Mm[b * 16 + c] = row[c] * g;
        Mm[256 + b] = g;
    }
}

// ---------------- fused v-GEMM + mix + bias + residual. Block: ALL 256 m x 16 n x 16 b.
// f32x4 staging, sigma-slot + row-padded LDS (conflict-light), double-buffered, 4 chunks of K=64.
__global__ __launch_bounds__(1024, 4) void k_fused(const unsigned short* __restrict__ WvF,
                                                   const float* __restrict__ x,
                                                   const float* __restrict__ bv,
                                                   const float* __restrict__ Mm,
                                                   float* __restrict__ out) {
    // [buf][bp][row 0..7][17 units of 16B] ; row stride 136 elems = 272 B (bank-rotated)
    __shared__ __align__(16) __bf16 XB[2][16][1088];      // 69632 B
    int n0 = blockIdx.x * 16;
    int t = threadIdx.x;
    int lane = t & 63, wid = t >> 6;      // wid = m-frag (rows wid*16..wid*16+15)
    int lr = lane & 15, kg = lane >> 4;
    int n4 = t & 3, sk = (t >> 2) & 63, bpg = t >> 8;
    int sigr = ((lr & 3) << 2) | (lr >> 2);

    f32x4 u[16];
    #pragma unroll
    for (int b = 0; b < 16; b++) u[b] = (f32x4){0.f, 0.f, 0.f, 0.f};

    f32x4 xv[4];
    #pragma unroll
    for (int bpi = 0; bpi < 4; bpi++)
        xv[bpi] = *(const f32x4*)(x + (size_t)(bpg * 4 + bpi) * DV + (size_t)sk * HW_ + n0 + n4 * 4);
    {
        int rowoff = (sk >> 3) * 136 + (sk & 7);
        #pragma unroll
        for (int bpi = 0; bpi < 4; bpi++) {
            __bf16* basep = &XB[0][bpg * 4 + bpi][rowoff];
            #pragma unroll
            for (int e = 0; e < 4; e++)
                basep[((e << 2) | n4) * 8] = (__bf16)xv[bpi][e];
        }
    }
    __syncthreads();

    for (int c = 0; c < 4; c++) {
        int cur = c & 1;
        if (c < 3) {
            #pragma unroll
            for (int bpi = 0; bpi < 4; bpi++)
                xv[bpi] = *(const f32x4*)(x + (size_t)(bpg * 4 + bpi) * DV + (size_t)((c + 1) * 64 + sk) * HW_ + n0 + n4 * 4);
        }
        #pragma unroll
        for (int sub = 0; sub < 2; sub++) {
            bf16x8 a = *(const bf16x8*)(WvF + (size_t)wid * 4096 + (c * 2 + sub) * 512 + lane * 8);
            const __bf16* bbase = &XB[cur][0][(sub * 4 + kg) * 136 + sigr * 8];
            #pragma unroll
            for (int bp = 0; bp < 16; bp++) {
                bf16x8 bb = *(const bf16x8*)(bbase + bp * 1088);
                u[bp] = __builtin_amdgcn_mfma_f32_16x16x32_bf16(a, bb, u[bp], 0, 0, 0);
            }
        }
        if (c < 3) {
            int nb = cur ^ 1;
            int rowoff = (sk >> 3) * 136 + (sk & 7);
            #pragma unroll
            for (int bpi = 0; bpi < 4; bpi++) {
                __bf16* basep = &XB[nb][bpg * 4 + bpi][rowoff];
                #pragma unroll
                for (int e = 0; e < 4; e++)
                    basep[((e << 2) | n4) * 8] = (__bf16)xv[bpi][e];
            }
        }
        __syncthreads();
    }

    // epilogue: mix u across batches (7-sparse), + rs*bv + residual, direct write
    int mrow0 = wid * 16 + kg * 4;
    f32x4 bv4 = (f32x4){bv[mrow0], bv[mrow0 + 1], bv[mrow0 + 2], bv[mrow0 + 3]};
    #pragma unroll
    for (int b = 0; b < 16; b++) {
        int h = b >> 2, w = b & 3;
        f32x4 mo = (f32x4){0.f, 0.f, 0.f, 0.f};
        #pragma unroll
        for (int g = 0; g < 4; g++) {
            if (g != h) mo += Mm[b * 16 + g * 4 + w] * u[g * 4 + w];
            mo += Mm[b * 16 + h * 4 + g] * u[h * 4 + g];
        }
        mo += Mm[256 + b] * bv4;
        #pragma unroll
        for (int i = 0; i < 4; i++) {
            size_t idx = (size_t)b * DV + (size_t)(mrow0 + i) * HW_ + n0 + lr;
            out[idx] = mo[i] + x[idx];
        }
    }
}

extern "C" void kernel_launch(void* const* d_in, const int* in_sizes, int n_in,
                              void* d_out, int out_size, void* d_ws, size_t ws_size,
                              hipStream_t stream) {
    (void)in_sizes; (void)n_in; (void)out_size; (void)ws_size;
    const float* x     = (const float*)d_in[0];
    const float* wq    = (const float*)d_in[1];
    const float* bq    = (const float*)d_in[2];
    const float* wk    = (const float*)d_in[3];
    const float* bk    = (const float*)d_in[4];
    const float* wv    = (const float*)d_in[5];
    const float* bv    = (const float*)d_in[6];
    const float* gamma = (const float*)d_in[7];

    char* ws = (char*)d_ws;
    // ws layout: WhF 32768 | WlF 32768 | WvF 131072 | QF 8388608 | KF 8388608 | Sp 131072 | Mm 1088
    unsigned short* WhF = (unsigned short*)(ws + 0);
    unsigned short* WlF = (unsigned short*)(ws + 32768);
    unsigned short* WvF = (unsigned short*)(ws + 65536);
    float*          QF  = (float*)(ws + 196608);
    float*          KF  = (float*)(ws + 8585216);
    float*          Sp  = (float*)(ws + 16973824);
    float*          Mm  = (float*)(ws + 17104896);
    float*          vo  = (float*)d_out;

    k_pack     <<<320, 256, 0, stream>>>(wq, wk, wv, WhF, WlF, WvF);
    k_gemm_qk  <<<dim3(64, 16), 256, 0, stream>>>(WhF, WlF, x, bq, bk, QF, KF);
    k_scores2  <<<256, 256, 0, stream>>>(QF, KF, Sp);
    k_softmax2 <<<1, 128, 0, stream>>>(Sp, gamma, Mm);
    k_fused    <<<256, 1024, 0, stream>>>(WvF, x, bv, Mm, vo);
}